// Round 6
// baseline (25.954 us; speedup 1.0000x reference)
//
#include <hip/hip_runtime.h>
#include <math.h>

#define NCH 8
#define KMIX 4
#define TRI 36
#define LOG_2PI 1.8378770664093453f

typedef float fvec4 __attribute__((ext_vector_type(4)));

// v_rcp_f32: ~2^-22 relative error, single instruction.
__device__ __forceinline__ float rcp_fast(float x) { return __builtin_amdgcn_rcpf(x); }

// Pin a wave-uniform value into an SGPR.
__device__ __forceinline__ float sgpr_f(float v) {
    return __uint_as_float(__builtin_amdgcn_readfirstlane(__float_as_uint(v)));
}

// Single fused kernel. Block = 256 threads = 4 waves; wave k owns component k.
//
// Prologue (per wave, all lanes redundant, fast-math ops only, ~500 cyc):
// compute Linv_k (packed tril), -b_k = -Linv_k@mu_k, and the additive
// constant c_k; pin all 45 floats into SGPRs via readfirstlane.
//
// Steady state per 256-voxel tile: wave k computes lp_k for all 256 voxels
// (4 slabs of 64) with SGPR-only constants -> ZERO constant memory traffic
// per voxel (this was the R1/R5 bottleneck: per-voxel uniform loads still
// move 64 lanes x data through the L1 return path). Exchange via LDS, each
// wave logsumexp-combines + nt-stores its 64-voxel quarter.
__global__ __launch_bounds__(256) void gmm_fused(const float* __restrict__ x,
                                                 const float* __restrict__ weights,
                                                 const float* __restrict__ loc,   // [N,K]
                                                 const float* __restrict__ sp,    // [TRI,K]
                                                 float* __restrict__ out,
                                                 int B, int nIter) {
    __shared__ float lp_lds[KMIX][256];

    const int tid  = threadIdx.x;
    const int wid  = tid >> 6;
    const int lane = tid & 63;
    const int k    = wid;           // component for this wave

    // ---------------- prologue ---------------------------------------------
    float w0 = weights[0], w1 = weights[1], w2 = weights[2], w3 = weights[3];
    float wk = (k == 0) ? w0 : (k == 1) ? w1 : (k == 2) ? w2 : w3;
    float wmax = fmaxf(fmaxf(w0, w1), fmaxf(w2, w3));
    float se = __expf(w0 - wmax) + __expf(w1 - wmax) +
               __expf(w2 - wmax) + __expf(w3 - wmax);
    float logw = wk - (wmax + __logf(se));

    float L[NCH][NCH];
    {
        int t = 0;
#pragma unroll
        for (int i = 0; i < NCH; ++i)
#pragma unroll
            for (int j = 0; j <= i; ++j)
                L[i][j] = sp[t++ * KMIX + k];   // wave-uniform loads, L1-hit
    }

    float rd[NCH];
    float logdet = 0.f;
#pragma unroll
    for (int i = 0; i < NCH; ++i) {
        rd[i] = rcp_fast(L[i][i]);
        logdet += __logf(L[i][i]);
    }

    // forward solve L * Li = I, column by column (lower triangular)
    float Li[NCH][NCH];
#pragma unroll
    for (int j = 0; j < NCH; ++j) {
#pragma unroll
        for (int i = j; i < NCH; ++i) {
            float s = (i == j) ? 1.f : 0.f;
#pragma unroll
            for (int m = 0; m < NCH; ++m)
                if (m >= j && m < i) s -= L[i][m] * Li[m][j];
            Li[i][j] = s * rd[i];
        }
    }

    float mu[NCH];
#pragma unroll
    for (int j = 0; j < NCH; ++j) mu[j] = loc[j * KMIX + k];

    float sLi[TRI], sNb[NCH];
    {
        int t = 0;
#pragma unroll
        for (int i = 0; i < NCH; ++i) {
            float b = 0.f;
#pragma unroll
            for (int j = 0; j <= i; ++j) {
                sLi[t] = sgpr_f(Li[i][j]);
                b += Li[i][j] * mu[j];
                ++t;
            }
            sNb[i] = sgpr_f(-b);
        }
    }
    const float sC = sgpr_f(logw - logdet - 0.5f * NCH * LOG_2PI);

    // ---------------- steady state -----------------------------------------
    const int base0 = blockIdx.x * (256 * nIter);
    for (int it = 0; it < nIter; ++it) {
        const int vbase = base0 + it * 256;

        float lpv[4];
#pragma unroll
        for (int s = 0; s < 4; ++s) {
            const int v = vbase + s * 64 + lane;
            float xv[NCH];
            if (v < B) {
                const fvec4* xp = reinterpret_cast<const fvec4*>(x + (size_t)v * NCH);
                fvec4 a0 = xp[0], a1 = xp[1];   // plain loads: line shared by 4 waves
                xv[0] = a0.x; xv[1] = a0.y; xv[2] = a0.z; xv[3] = a0.w;
                xv[4] = a1.x; xv[5] = a1.y; xv[6] = a1.z; xv[7] = a1.w;
            } else {
#pragma unroll
                for (int i = 0; i < NCH; ++i) xv[i] = 0.f;
            }
            float maha = 0.f;
            int t = 0;
#pragma unroll
            for (int i = 0; i < NCH; ++i) {
                float z = sNb[i];
#pragma unroll
                for (int j = 0; j <= i; ++j) {
                    z = fmaf(sLi[t], xv[j], z);
                    ++t;
                }
                maha = fmaf(z, z, maha);
            }
            lpv[s] = fmaf(-0.5f, maha, sC);
        }

        __syncthreads();   // previous tile's combine reads finished
#pragma unroll
        for (int s = 0; s < 4; ++s) lp_lds[k][s * 64 + lane] = lpv[s];
        __syncthreads();   // all components visible

        const int vo = wid * 64 + lane;
        const int v  = vbase + vo;
        float l0 = lp_lds[0][vo], l1 = lp_lds[1][vo];
        float l2 = lp_lds[2][vo], l3 = lp_lds[3][vo];
        if (v < B) {
            float mx = fmaxf(fmaxf(l0, l1), fmaxf(l2, l3));
            float s2 = __expf(l0 - mx) + __expf(l1 - mx) +
                       __expf(l2 - mx) + __expf(l3 - mx);
            __builtin_nontemporal_store(mx + __logf(s2), out + v);
        }
    }
}

extern "C" void kernel_launch(void* const* d_in, const int* in_sizes, int n_in,
                              void* d_out, int out_size, void* d_ws, size_t ws_size,
                              hipStream_t stream) {
    const float* x       = (const float*)d_in[0];   // [B, N]
    const float* weights = (const float*)d_in[1];   // [K]
    const float* loc     = (const float*)d_in[2];   // [N, K]
    const float* sp      = (const float*)d_in[3];   // [TRI, K]
    float* out = (float*)d_out;

    const int B = in_sizes[0] / NCH;

    const int blocks = 2048;                                     // 8 blocks/CU
    const int nIter  = (B + 256 * blocks - 1) / (256 * blocks);  // = 4 for B=2^21

    gmm_fused<<<blocks, 256, 0, stream>>>(x, weights, loc, sp, out, B, nIter);
}

// Round 7
// 24.462 us; speedup vs baseline: 1.0610x; 1.0610x over previous
//
#include <hip/hip_runtime.h>
#include <math.h>

#define NCH 8
#define KMIX 4
#define TRI 36
#define CSTRIDE 48       // per-component: 36 Linv + 8 (-b) + 1 c + 3 pad (16B aligned)
#define LOG_2PI 1.8378770664093453f

typedef float fvec4 __attribute__((ext_vector_type(4)));

__device__ __forceinline__ float rcp_fast(float x) { return __builtin_amdgcn_rcpf(x); }

// ---------------------------------------------------------------------------
// Setup kernel: 4 threads, one per mixture component k. Fast-math only —
// this node serializes ahead of the main kernel, so its dependent-chain
// latency is on the critical path.
// ws[k*48 + 0..35]  = Linv (packed row-major tril)
// ws[k*48 + 36..43] = -Linv @ mu
// ws[k*48 + 44]     = logsoftmax(w)_k - logdet L - 0.5*N*log(2pi)
// ---------------------------------------------------------------------------
__global__ void gmm_setup(const float* __restrict__ weights,
                          const float* __restrict__ loc,          // [N, K]
                          const float* __restrict__ sp,           // [TRI, K]
                          float* __restrict__ ws) {
    int k = threadIdx.x;
    if (k >= KMIX) return;

    float wmax = weights[0];
    for (int i = 1; i < KMIX; ++i) wmax = fmaxf(wmax, weights[i]);
    float se = 0.f;
    for (int i = 0; i < KMIX; ++i) se += __expf(weights[i] - wmax);
    float logw = weights[k] - (wmax + __logf(se));

    float L[NCH][NCH];
    int t = 0;
    for (int i = 0; i < NCH; ++i)
        for (int j = 0; j <= i; ++j)
            L[i][j] = sp[t++ * KMIX + k];

    float rd[NCH];
    float logdet = 0.f;
    for (int i = 0; i < NCH; ++i) {
        rd[i] = rcp_fast(L[i][i]);
        logdet += __logf(L[i][i]);
    }

    float Li[NCH][NCH];
    for (int j = 0; j < NCH; ++j) {
        for (int i = j; i < NCH; ++i) {
            float s = (i == j) ? 1.f : 0.f;
            for (int m = j; m < i; ++m) s -= L[i][m] * Li[m][j];
            Li[i][j] = s * rd[i];
        }
    }

    float mu[NCH];
    for (int j = 0; j < NCH; ++j) mu[j] = loc[j * KMIX + k];

    float* o = ws + k * CSTRIDE;
    t = 0;
    for (int i = 0; i < NCH; ++i)
        for (int j = 0; j <= i; ++j)
            o[t++] = Li[i][j];
    for (int i = 0; i < NCH; ++i) {
        float b = 0.f;
        for (int j = 0; j <= i; ++j) b += Li[i][j] * mu[j];
        o[TRI + i] = -b;                       // store -b: main adds directly
    }
    o[44] = logw - logdet - 0.5f * NCH * LOG_2PI;
    o[45] = 0.f; o[46] = 0.f; o[47] = 0.f;
}

// ---------------------------------------------------------------------------
// Main kernel: 1 voxel per thread (best-measured structure, R5 = 24.7 us).
// Constants fetched as 12 float4 per component from uniform addresses
// (L1-hit, one request per wave each). x/out nontemporal (streamed once).
// ---------------------------------------------------------------------------
__global__ __launch_bounds__(256) void gmm_main(const float* __restrict__ x,
                                                const float* __restrict__ cst,
                                                float* __restrict__ out,
                                                int B) {
    int v = blockIdx.x * blockDim.x + threadIdx.x;
    if (v >= B) return;

    const fvec4* xp = reinterpret_cast<const fvec4*>(x + (size_t)v * NCH);
    fvec4 a0 = __builtin_nontemporal_load(xp);
    fvec4 a1 = __builtin_nontemporal_load(xp + 1);
    float xv[NCH] = {a0.x, a0.y, a0.z, a0.w, a1.x, a1.y, a1.z, a1.w};

    float lp[KMIX];
#pragma unroll
    for (int k = 0; k < KMIX; ++k) {
        const fvec4* cp = reinterpret_cast<const fvec4*>(cst + k * CSTRIDE);
        float cc[CSTRIDE];
#pragma unroll
        for (int r = 0; r < 12; ++r) {
            fvec4 q = cp[r];
            cc[4 * r + 0] = q.x; cc[4 * r + 1] = q.y;
            cc[4 * r + 2] = q.z; cc[4 * r + 3] = q.w;
        }
        float maha = 0.f;
        int t = 0;
#pragma unroll
        for (int i = 0; i < NCH; ++i) {
            float z = cc[TRI + i];            // already -b_i
#pragma unroll
            for (int j = 0; j <= i; ++j) {
                z = fmaf(cc[t], xv[j], z);
                ++t;
            }
            maha = fmaf(z, z, maha);
        }
        lp[k] = fmaf(-0.5f, maha, cc[44]);
    }

    float mx = fmaxf(fmaxf(lp[0], lp[1]), fmaxf(lp[2], lp[3]));
    float s = __expf(lp[0] - mx) + __expf(lp[1] - mx) +
              __expf(lp[2] - mx) + __expf(lp[3] - mx);
    __builtin_nontemporal_store(mx + __logf(s), out + v);
}

extern "C" void kernel_launch(void* const* d_in, const int* in_sizes, int n_in,
                              void* d_out, int out_size, void* d_ws, size_t ws_size,
                              hipStream_t stream) {
    const float* x       = (const float*)d_in[0];   // [B, N]
    const float* weights = (const float*)d_in[1];   // [K]
    const float* loc     = (const float*)d_in[2];   // [N, K]
    const float* sp      = (const float*)d_in[3];   // [TRI, K]
    float* out = (float*)d_out;
    float* ws  = (float*)d_ws;

    int B = in_sizes[0] / NCH;

    gmm_setup<<<1, 64, 0, stream>>>(weights, loc, sp, ws);

    int threads = 256;
    int blocks = (B + threads - 1) / threads;
    gmm_main<<<blocks, threads, 0, stream>>>(x, ws, out, B);
}